// Round 4
// baseline (48.150 us; speedup 1.0000x reference)
//
#include <hip/hip_runtime.h>
#include <hip/hip_cooperative_groups.h>

namespace cg = cooperative_groups;

#define MARGIN 1.0f
#define MAXC 128
#define NB   256          // total blocks (1 per CU, cooperative)
#define NBM  255          // blocks 0..NBM-1: close+cls; block NBM: dist
#define TPB  512          // 8 waves/block

__device__ __forceinline__ float wave_reduce_sum(float v) {
    #pragma unroll
    for (int off = 32; off > 0; off >>= 1)
        v += __shfl_down(v, off, 64);
    return v;
}

// valid in thread 0 only; safe to call repeatedly (s8 reuse fenced)
__device__ __forceinline__ float block_reduce_sum(float v, float* s8) {
    int lane = threadIdx.x & 63, wid = threadIdx.x >> 6;
    v = wave_reduce_sum(v);
    if (lane == 0) s8[wid] = v;
    __syncthreads();
    float r = 0.f;
    if (wid == 0) {
        r = (lane < (TPB / 64)) ? s8[lane] : 0.f;
        r = wave_reduce_sum(r);
    }
    __syncthreads();
    return r;
}

// ws layout (floats), every cell overwritten each launch (poison-safe):
//   ws[blk]        blk<NBM : close per-block weighted partial
//   ws[NBM+blk]    blk<NBM : cls per-block partial
//   ws[2*NBM]              : loss_dist
__global__ void fused(const float* __restrict__ z, const float* __restrict__ w,
                      const float* __restrict__ o, const int* __restrict__ y,
                      float* __restrict__ ws, float* __restrict__ out,
                      int B, int C, int D) {
    cg::grid_group grid = cg::this_grid();
    const int t = threadIdx.x;
    const int blk = blockIdx.x;
    __shared__ float s8[TPB / 64];

    if (blk == NBM) {
        // ---- dist: S_i = (sumNorm + C*||w_i||^2 - 2*w_i·colsum) / ((C-1)*D) ----
        __shared__ float s_vec[128];   // column sums (D == 128)
        __shared__ float s_p[TPB];
        __shared__ float s_bc;
        int d = t & 127, qq = t >> 7;          // 4 row-stripes
        float a = 0.f;
        for (int j = qq; j < C; j += 4) a += w[j * D + d];
        s_p[t] = a;
        __syncthreads();
        if (t < 128) s_vec[t] = s_p[t] + s_p[t + 128] + s_p[t + 256] + s_p[t + 384];
        __syncthreads();

        float norm_i = 0.f, dot_i = 0.f;
        if (t < C) {
            const float4* wp = reinterpret_cast<const float4*>(w + (size_t)t * D);
            for (int k = 0; k < D / 4; ++k) {
                float4 v = wp[k];
                norm_i += v.x*v.x + v.y*v.y + v.z*v.z + v.w*v.w;
                dot_i  += v.x*s_vec[4*k] + v.y*s_vec[4*k+1]
                        + v.z*s_vec[4*k+2] + v.w*s_vec[4*k+3];
            }
        }
        float sumNorm = block_reduce_sum((t < C) ? norm_i : 0.f, s8);
        if (t == 0) s_bc = sumNorm;
        __syncthreads();
        sumNorm = s_bc;

        float contrib = 0.f;
        if (t < C) {
            float S = (sumNorm + (float)C * norm_i - 2.f * dot_i)
                      / ((float)(C - 1) * (float)D);
            contrib = fmaxf(MARGIN - S, 0.f) / (float)C;
        }
        contrib = block_reduce_sum(contrib, s8);
        if (t == 0) ws[2 * NBM] = contrib;
    } else {
        // ---- full-y histogram (redundant per block; L2-hot, no zeroing deps) ----
        __shared__ int   hist[MAXC];
        __shared__ float wgt[MAXC];
        for (int i = t; i < C; i += TPB) hist[i] = 0;
        __syncthreads();
        const int4* y4 = reinterpret_cast<const int4*>(y);
        for (int i = t; i < B / 4; i += TPB) {
            int4 v = y4[i];
            atomicAdd(&hist[v.x], 1);
            atomicAdd(&hist[v.y], 1);
            atomicAdd(&hist[v.z], 1);
            atomicAdd(&hist[v.w], 1);
        }
        __syncthreads();
        for (int c = t; c < C; c += TPB) wgt[c] = 1.f / ((float)hist[c] * (float)D);
        __syncthreads();

        // ---- close: quarter-wave (16 lanes) per sample, 2x float4 each ----
        const int lane16 = t & 15;
        const int g  = blk * (TPB / 16) + (t >> 4);   // 255*32 = 8160 groups
        const int NG = NBM * (TPB / 16);
        float closeAcc = 0.f;
        for (int s = g; s < B; s += NG) {
            int yb = y[s];
            const float4* zp = reinterpret_cast<const float4*>(z + ((size_t)s * C + yb) * D);
            const float4* wp = reinterpret_cast<const float4*>(w + (size_t)yb * D);
            float4 a0 = zp[lane16],      b0 = wp[lane16];
            float4 a1 = zp[lane16 + 16], b1 = wp[lane16 + 16];
            float e0 = a0.x-b0.x, e1 = a0.y-b0.y, e2 = a0.z-b0.z, e3 = a0.w-b0.w;
            float f0 = a1.x-b1.x, f1 = a1.y-b1.y, f2 = a1.z-b1.z, f3 = a1.w-b1.w;
            float v = e0*e0 + e1*e1 + e2*e2 + e3*e3
                    + f0*f0 + f1*f1 + f2*f2 + f3*f3;
            v += __shfl_xor(v, 1, 64);
            v += __shfl_xor(v, 2, 64);
            v += __shfl_xor(v, 4, 64);
            v += __shfl_xor(v, 8, 64);
            if (lane16 == 0) closeAcc += v * wgt[yb];
        }

        // ---- cls: grid-stride float4 over o (C%4==0 -> never crosses a row) ----
        const int nq = B * C / 4, perRow = C >> 2;
        float clsAcc = 0.f;
        for (int qi = blk * TPB + t; qi < nq; qi += NBM * TPB) {
            int b  = qi / perRow;
            int c0 = (qi - b * perRow) * 4;
            float4 v = reinterpret_cast<const float4*>(o)[qi];
            int yb = y[b];
            float e0 = v.x - ((c0 + 0 == yb) ? 1.f : 0.f);
            float e1 = v.y - ((c0 + 1 == yb) ? 1.f : 0.f);
            float e2 = v.z - ((c0 + 2 == yb) ? 1.f : 0.f);
            float e3 = v.w - ((c0 + 3 == yb) ? 1.f : 0.f);
            clsAcc += e0*e0 + e1*e1 + e2*e2 + e3*e3;
        }

        float cp = block_reduce_sum(closeAcc, s8);
        if (t == 0) ws[blk] = cp;
        float kp = block_reduce_sum(clsAcc, s8);
        if (t == 0) ws[NBM + blk] = kp;
    }

    grid.sync();

    if (blk == 0) {
        float c = 0.f, k = 0.f;
        for (int i = t; i < NBM; i += TPB) {
            c += ws[i];
            k += ws[NBM + i];
        }
        c = block_reduce_sum(c, s8);
        k = block_reduce_sum(k, s8);
        if (t == 0) {
            float cls  = k / ((float)B * (float)C);
            float dist = ws[2 * NBM];
            out[0] = cls + c + dist;
            out[1] = cls;
            out[2] = c;
            out[3] = dist;
        }
    }
}

extern "C" void kernel_launch(void* const* d_in, const int* in_sizes, int n_in,
                              void* d_out, int out_size, void* d_ws, size_t ws_size,
                              hipStream_t stream) {
    const float* z = (const float*)d_in[0];
    const float* w = (const float*)d_in[1];
    const float* o = (const float*)d_in[2];
    const int*   y = (const int*)d_in[3];
    float* out = (float*)d_out;
    float* ws  = (float*)d_ws;

    int B = in_sizes[3];              // 8192
    int C = in_sizes[2] / B;          // 100
    int D = in_sizes[1] / C;          // 128

    void* args[] = {(void*)&z, (void*)&w, (void*)&o, (void*)&y,
                    (void*)&ws, (void*)&out, (void*)&B, (void*)&C, (void*)&D};
    hipLaunchCooperativeKernel((const void*)fused, dim3(NB), dim3(TPB),
                               args, 0, stream);
}

// Round 5
// 13.676 us; speedup vs baseline: 3.5207x; 3.5207x over previous
//
#include <hip/hip_runtime.h>

#define MARGIN 1.0f
#define MAXC 128
#define NBM  256          // main blocks; block NBM does dist -> grid = NBM+1
#define TPB  512          // 8 waves/block

__device__ __forceinline__ float wave_reduce_sum(float v) {
    #pragma unroll
    for (int off = 32; off > 0; off >>= 1)
        v += __shfl_down(v, off, 64);
    return v;
}

// valid in thread 0 only; safe to call repeatedly (s8 reuse fenced)
__device__ __forceinline__ float block_reduce_sum(float v, float* s8) {
    int lane = threadIdx.x & 63, wid = threadIdx.x >> 6;
    v = wave_reduce_sum(v);
    if (lane == 0) s8[wid] = v;
    __syncthreads();
    float r = 0.f;
    if (wid == 0) {
        r = (lane < (TPB / 64)) ? s8[lane] : 0.f;
        r = wave_reduce_sum(r);
    }
    __syncthreads();
    return r;
}

// ws layout (floats), every cell overwritten each launch (poison-safe, no zeroing):
//   ws[blk]        blk<NBM : close per-block weighted partial
//   ws[NBM+blk]    blk<NBM : cls per-block partial
//   ws[2*NBM]              : loss_dist
__global__ void k1_main(const float* __restrict__ z, const float* __restrict__ w,
                        const float* __restrict__ o, const int* __restrict__ y,
                        float* __restrict__ ws, int B, int C, int D) {
    const int t = threadIdx.x;
    const int blk = blockIdx.x;
    __shared__ float s8[TPB / 64];

    if (blk == NBM) {
        // ---- dist: S_i = (sumNorm + C*||w_i||^2 - 2*w_i·colsum) / ((C-1)*D) ----
        __shared__ float s_vec[128];   // column sums (D == 128)
        __shared__ float s_p[TPB];
        __shared__ float s_bc;
        int d = t & 127, qq = t >> 7;          // 4 row-stripes
        float a = 0.f;
        for (int j = qq; j < C; j += 4) a += w[j * D + d];
        s_p[t] = a;
        __syncthreads();
        if (t < 128) s_vec[t] = s_p[t] + s_p[t + 128] + s_p[t + 256] + s_p[t + 384];
        __syncthreads();

        float norm_i = 0.f, dot_i = 0.f;
        if (t < C) {
            const float4* wp = reinterpret_cast<const float4*>(w + (size_t)t * D);
            for (int k = 0; k < D / 4; ++k) {
                float4 v = wp[k];
                norm_i += v.x*v.x + v.y*v.y + v.z*v.z + v.w*v.w;
                dot_i  += v.x*s_vec[4*k] + v.y*s_vec[4*k+1]
                        + v.z*s_vec[4*k+2] + v.w*s_vec[4*k+3];
            }
        }
        float sumNorm = block_reduce_sum((t < C) ? norm_i : 0.f, s8);
        if (t == 0) s_bc = sumNorm;
        __syncthreads();
        sumNorm = s_bc;

        float contrib = 0.f;
        if (t < C) {
            float S = (sumNorm + (float)C * norm_i - 2.f * dot_i)
                      / ((float)(C - 1) * (float)D);
            contrib = fmaxf(MARGIN - S, 0.f) / (float)C;
        }
        contrib = block_reduce_sum(contrib, s8);
        if (t == 0) ws[2 * NBM] = contrib;
        return;
    }

    // ---- per-block y histogram (y is 32KB, L1/L2-hot; no cross-block deps) ----
    __shared__ int   hist[MAXC];
    __shared__ float wgt[MAXC];
    for (int i = t; i < C; i += TPB) hist[i] = 0;
    __syncthreads();
    const int4* y4 = reinterpret_cast<const int4*>(y);
    for (int i = t; i < B / 4; i += TPB) {
        int4 v = y4[i];
        atomicAdd(&hist[v.x], 1);
        atomicAdd(&hist[v.y], 1);
        atomicAdd(&hist[v.z], 1);
        atomicAdd(&hist[v.w], 1);
    }
    __syncthreads();
    for (int c = t; c < C; c += TPB) wgt[c] = 1.f / ((float)hist[c] * (float)D);
    __syncthreads();

    // ---- close: 16-lane group per sample, 2x float4/lane; weighted scalar sum ----
    const int lane16 = t & 15;
    const int NG = NBM * (TPB / 16);              // 8192 groups == B
    float closeAcc = 0.f;
    for (int s = blk * (TPB / 16) + (t >> 4); s < B; s += NG) {
        int yb = y[s];
        const float4* zp = reinterpret_cast<const float4*>(z + ((size_t)s * C + yb) * D);
        const float4* wp = reinterpret_cast<const float4*>(w + (size_t)yb * D);
        float4 a0 = zp[lane16],      b0 = wp[lane16];
        float4 a1 = zp[lane16 + 16], b1 = wp[lane16 + 16];
        float e0 = a0.x-b0.x, e1 = a0.y-b0.y, e2 = a0.z-b0.z, e3 = a0.w-b0.w;
        float f0 = a1.x-b1.x, f1 = a1.y-b1.y, f2 = a1.z-b1.z, f3 = a1.w-b1.w;
        float v = e0*e0 + e1*e1 + e2*e2 + e3*e3
                + f0*f0 + f1*f1 + f2*f2 + f3*f3;
        v += __shfl_xor(v, 1, 64);
        v += __shfl_xor(v, 2, 64);
        v += __shfl_xor(v, 4, 64);
        v += __shfl_xor(v, 8, 64);
        if (lane16 == 0) closeAcc += v * wgt[yb];
    }

    // ---- cls: grid-stride float4 over o (C%4==0 -> never crosses a row) ----
    const int nq = B * C / 4, perRow = C >> 2;
    float clsAcc = 0.f;
    for (int qi = blk * TPB + t; qi < nq; qi += NBM * TPB) {
        int b  = qi / perRow;
        int c0 = (qi - b * perRow) * 4;
        float4 v = reinterpret_cast<const float4*>(o)[qi];
        int yb = y[b];
        float e0 = v.x - ((c0 + 0 == yb) ? 1.f : 0.f);
        float e1 = v.y - ((c0 + 1 == yb) ? 1.f : 0.f);
        float e2 = v.z - ((c0 + 2 == yb) ? 1.f : 0.f);
        float e3 = v.w - ((c0 + 3 == yb) ? 1.f : 0.f);
        clsAcc += e0*e0 + e1*e1 + e2*e2 + e3*e3;
    }

    float cp = block_reduce_sum(closeAcc, s8);
    if (t == 0) ws[blk] = cp;
    float kp = block_reduce_sum(clsAcc, s8);
    if (t == 0) ws[NBM + blk] = kp;
}

// K2: one block of 256 — reads 2*NBM+1 floats (~2KB), combines, writes out.
__global__ void k2_final(const float* __restrict__ ws, float* __restrict__ out,
                         int B, int C) {
    int t = threadIdx.x;
    int lane = t & 63, wid = t >> 6;

    float c = 0.f, k = 0.f;
    for (int i = t; i < NBM; i += blockDim.x) {
        c += ws[i];
        k += ws[NBM + i];
    }
    c = wave_reduce_sum(c);
    k = wave_reduce_sum(k);
    __shared__ float pc[4], pk[4];
    if (lane == 0) { pc[wid] = c; pk[wid] = k; }
    __syncthreads();
    if (t == 0) {
        float close = pc[0] + pc[1] + pc[2] + pc[3];
        float cls   = (pk[0] + pk[1] + pk[2] + pk[3]) / ((float)B * (float)C);
        float dist  = ws[2 * NBM];
        out[0] = cls + close + dist;
        out[1] = cls;
        out[2] = close;
        out[3] = dist;
    }
}

extern "C" void kernel_launch(void* const* d_in, const int* in_sizes, int n_in,
                              void* d_out, int out_size, void* d_ws, size_t ws_size,
                              hipStream_t stream) {
    const float* z = (const float*)d_in[0];
    const float* w = (const float*)d_in[1];
    const float* o = (const float*)d_in[2];
    const int*   y = (const int*)d_in[3];
    float* out = (float*)d_out;
    float* ws  = (float*)d_ws;

    const int B = in_sizes[3];              // 8192
    const int C = in_sizes[2] / B;          // 100
    const int D = in_sizes[1] / C;          // 128

    k1_main<<<NBM + 1, TPB, 0, stream>>>(z, w, o, y, ws, B, C, D);
    k2_final<<<1, 256, 0, stream>>>(ws, out, B, C);
}

// Round 6
// 13.406 us; speedup vs baseline: 3.5917x; 1.0201x over previous
//
#include <hip/hip_runtime.h>

#define MARGIN 1.0f
// Problem sizes are fixed by setup_inputs(): z[8192,100,128] f32, w[100,128], o[8192,100], y[8192]
#define BB  8192
#define CC  100
#define DD  128
#define NBM 256          // main blocks; block NBM does dist -> grid = NBM+1
#define TPB 512          // 8 waves/block

__device__ __forceinline__ float wave_reduce_sum(float v) {
    #pragma unroll
    for (int off = 32; off > 0; off >>= 1)
        v += __shfl_down(v, off, 64);
    return v;
}

// valid in thread 0 only; safe to call repeatedly
__device__ __forceinline__ float block_reduce_sum(float v, float* s8) {
    int lane = threadIdx.x & 63, wid = threadIdx.x >> 6;
    v = wave_reduce_sum(v);
    if (lane == 0) s8[wid] = v;
    __syncthreads();
    float r = 0.f;
    if (wid == 0) {
        r = (lane < (TPB / 64)) ? s8[lane] : 0.f;
        r = wave_reduce_sum(r);
    }
    __syncthreads();
    return r;
}

// ws layout (floats), every cell overwritten each launch (poison-safe, no zeroing):
//   ws[blk]        blk<NBM : close per-block weighted partial
//   ws[NBM+blk]    blk<NBM : cls per-block partial
//   ws[2*NBM]              : loss_dist
__global__ void __launch_bounds__(TPB) k1_main(
        const float* __restrict__ z, const float* __restrict__ w,
        const float* __restrict__ o, const int* __restrict__ y,
        float* __restrict__ ws) {
    const int t = threadIdx.x;
    const int blk = blockIdx.x;

    if (blk == NBM) {
        // ---- dist: S_i = (sumNorm + C*||w_i||^2 - 2*w_i·colsum) / ((C-1)*D) ----
        __shared__ float s8[TPB / 64];
        __shared__ float s_vec[DD];    // column sums
        __shared__ float s_p[TPB];
        __shared__ float s_bc;
        int d = t & 127, qq = t >> 7;          // 4 row-stripes
        float a = 0.f;
        for (int j = qq; j < CC; j += 4) a += w[j * DD + d];
        s_p[t] = a;
        __syncthreads();
        if (t < 128) s_vec[t] = s_p[t] + s_p[t + 128] + s_p[t + 256] + s_p[t + 384];
        __syncthreads();

        float norm_i = 0.f, dot_i = 0.f;
        if (t < CC) {
            const float4* wp = reinterpret_cast<const float4*>(w + (size_t)t * DD);
            #pragma unroll 8
            for (int k = 0; k < DD / 4; ++k) {
                float4 v = wp[k];
                norm_i += v.x*v.x + v.y*v.y + v.z*v.z + v.w*v.w;
                dot_i  += v.x*s_vec[4*k] + v.y*s_vec[4*k+1]
                        + v.z*s_vec[4*k+2] + v.w*s_vec[4*k+3];
            }
        }
        float sumNorm = block_reduce_sum((t < CC) ? norm_i : 0.f, s8);
        if (t == 0) s_bc = sumNorm;
        __syncthreads();
        sumNorm = s_bc;

        float contrib = 0.f;
        if (t < CC) {
            float S = (sumNorm + (float)CC * norm_i - 2.f * dot_i)
                      / ((float)(CC - 1) * (float)DD);
            contrib = fmaxf(MARGIN - S, 0.f) / (float)CC;
        }
        contrib = block_reduce_sum(contrib, s8);
        if (t == 0) ws[2 * NBM] = contrib;
        return;
    }

    // =========== main block: issue ALL global loads in one latency window ===========
    const int lane16 = t & 15;
    const int s = blk * (TPB / 16) + (t >> 4);       // one sample per 16-lane group
    int yb = y[s];                                    // broadcast within group

    // close gather (depends on yb)
    const float4* zp = reinterpret_cast<const float4*>(z + ((size_t)s * CC + yb) * DD);
    const float4* wp = reinterpret_cast<const float4*>(w + (size_t)yb * DD);
    float4 a0 = zp[lane16];
    float4 a1 = zp[lane16 + 16];
    float4 b0 = wp[lane16];
    float4 b1 = wp[lane16 + 16];

    // cls prefetch: 1-2 float4 of o per thread
    const float4* o4 = reinterpret_cast<const float4*>(o);
    const int nq = BB * CC / 4;                       // 204800
    const int qi  = blk * TPB + t;                    // < 131072 < nq
    const int qi2 = qi + NBM * TPB;
    float4 ov0 = o4[qi];
    const bool has2 = (qi2 < nq);
    float4 ov1 = has2 ? o4[qi2] : make_float4(0.f, 0.f, 0.f, 0.f);

    // y-histogram slice into registers (16 labels/thread, coalesced int4)
    const int4* y4 = reinterpret_cast<const int4*>(y);
    int4 r0 = y4[t];
    int4 r1 = y4[t + 512];
    int4 r2 = y4[t + 1024];
    int4 r3 = y4[t + 1536];

    // ---- LDS histogram (overlaps the in-flight global loads) ----
    __shared__ int hist[128];
    if (t < 128) hist[t] = 0;
    __syncthreads();
    atomicAdd(&hist[r0.x], 1); atomicAdd(&hist[r0.y], 1);
    atomicAdd(&hist[r0.z], 1); atomicAdd(&hist[r0.w], 1);
    atomicAdd(&hist[r1.x], 1); atomicAdd(&hist[r1.y], 1);
    atomicAdd(&hist[r1.z], 1); atomicAdd(&hist[r1.w], 1);
    atomicAdd(&hist[r2.x], 1); atomicAdd(&hist[r2.y], 1);
    atomicAdd(&hist[r2.z], 1); atomicAdd(&hist[r2.w], 1);
    atomicAdd(&hist[r3.x], 1); atomicAdd(&hist[r3.y], 1);
    atomicAdd(&hist[r3.z], 1); atomicAdd(&hist[r3.w], 1);
    __syncthreads();

    // ---- cls consume ----
    const int perRow = CC / 4;                        // 25, compile-time constant
    float clsAcc;
    {
        int b  = qi / perRow;
        int c0 = (qi - b * perRow) * 4;
        int yv = y[b];                                // L1-hot
        float e0 = ov0.x - ((c0 + 0 == yv) ? 1.f : 0.f);
        float e1 = ov0.y - ((c0 + 1 == yv) ? 1.f : 0.f);
        float e2 = ov0.z - ((c0 + 2 == yv) ? 1.f : 0.f);
        float e3 = ov0.w - ((c0 + 3 == yv) ? 1.f : 0.f);
        clsAcc = e0*e0 + e1*e1 + e2*e2 + e3*e3;
    }
    if (has2) {
        int b  = qi2 / perRow;
        int c0 = (qi2 - b * perRow) * 4;
        int yv = y[b];
        float e0 = ov1.x - ((c0 + 0 == yv) ? 1.f : 0.f);
        float e1 = ov1.y - ((c0 + 1 == yv) ? 1.f : 0.f);
        float e2 = ov1.z - ((c0 + 2 == yv) ? 1.f : 0.f);
        float e3 = ov1.w - ((c0 + 3 == yv) ? 1.f : 0.f);
        clsAcc += e0*e0 + e1*e1 + e2*e2 + e3*e3;
    }

    // ---- close consume ----
    float e0 = a0.x-b0.x, e1 = a0.y-b0.y, e2 = a0.z-b0.z, e3 = a0.w-b0.w;
    float f0 = a1.x-b1.x, f1 = a1.y-b1.y, f2 = a1.z-b1.z, f3 = a1.w-b1.w;
    float v = e0*e0 + e1*e1 + e2*e2 + e3*e3
            + f0*f0 + f1*f1 + f2*f2 + f3*f3;
    v += __shfl_xor(v, 1, 64);
    v += __shfl_xor(v, 2, 64);
    v += __shfl_xor(v, 4, 64);
    v += __shfl_xor(v, 8, 64);
    float closeAcc = 0.f;
    if (lane16 == 0)
        closeAcc = v / ((float)hist[yb] * (float)DD);

    // ---- combined block reduction (one LDS round) ----
    const int lane = t & 63, wid = t >> 6;
    float v0 = closeAcc, v1 = clsAcc;
    #pragma unroll
    for (int off = 32; off > 0; off >>= 1) {
        v0 += __shfl_down(v0, off, 64);
        v1 += __shfl_down(v1, off, 64);
    }
    __shared__ float sc[TPB / 64], sk[TPB / 64];
    if (lane == 0) { sc[wid] = v0; sk[wid] = v1; }
    __syncthreads();
    if (t == 0) {
        float c = 0.f, k = 0.f;
        #pragma unroll
        for (int i = 0; i < TPB / 64; ++i) { c += sc[i]; k += sk[i]; }
        ws[blk] = c;
        ws[NBM + blk] = k;
    }
}

// K2: one wave — reads 513 floats, combines, writes out. No LDS, no barrier.
__global__ void __launch_bounds__(64) k2_final(const float* __restrict__ ws,
                                               float* __restrict__ out) {
    int lane = threadIdx.x;
    const float4* p = reinterpret_cast<const float4*>(ws);
    float4 a = p[lane];          // close partials [0,256)
    float4 b = p[64 + lane];     // cls partials [256,512)
    float c = a.x + a.y + a.z + a.w;
    float k = b.x + b.y + b.z + b.w;
    #pragma unroll
    for (int off = 32; off > 0; off >>= 1) {
        c += __shfl_down(c, off, 64);
        k += __shfl_down(k, off, 64);
    }
    if (lane == 0) {
        float cls  = k / ((float)BB * (float)CC);
        float dist = ws[2 * NBM];
        out[0] = cls + c + dist;
        out[1] = cls;
        out[2] = c;
        out[3] = dist;
    }
}

extern "C" void kernel_launch(void* const* d_in, const int* in_sizes, int n_in,
                              void* d_out, int out_size, void* d_ws, size_t ws_size,
                              hipStream_t stream) {
    const float* z = (const float*)d_in[0];
    const float* w = (const float*)d_in[1];
    const float* o = (const float*)d_in[2];
    const int*   y = (const int*)d_in[3];
    float* out = (float*)d_out;
    float* ws  = (float*)d_ws;

    k1_main<<<NBM + 1, TPB, 0, stream>>>(z, w, o, y, ws);
    k2_final<<<1, 64, 0, stream>>>(ws, out);
}